// Round 3
// baseline (828.192 us; speedup 1.0000x reference)
//
#include <hip/hip_runtime.h>
#include <math.h>

// VectorQuantizer: inputs [64,32,32,64] f32, codebook [64,512] f32.
// Outputs (flat f32): ste[4194304], perplexity, codebook_loss, commitment_loss.
//
// ws layout (floats): Cn[512] | cbT[512*64] | counts[512] (as uint) | lossSum[1]

#define NUM_K   512
#define DIM     64
#define NROWS   65536
#define KT      256      // codes per LDS tile: 64*256*4 = 64 KB (static max)
#define TR      8        // rows per wave
#define ROWTILE 64       // rows per block (8 waves * 8 rows)
#define NBLOCKS (NROWS / ROWTILE)   // 1024
#define NELEM   (NROWS * DIM)

__global__ __launch_bounds__(512) void vq_prep(const float* __restrict__ cb,
                                               float* __restrict__ Cn,
                                               float* __restrict__ cbT,
                                               unsigned int* __restrict__ counts,
                                               float* __restrict__ lossSum)
{
    int k = threadIdx.x;  // 0..511
    float a = 0.0f;
    #pragma unroll
    for (int d = 0; d < DIM; ++d) {
        float v = cb[d * NUM_K + k];        // coalesced across k
        a = fmaf(v, v, a);
        cbT[k * DIM + d] = v;               // transposed copy for row gathers
    }
    Cn[k] = a;                              // ||e_k||^2, sequential-d order
    counts[k] = 0u;
    if (k == 0) *lossSum = 0.0f;
}

__global__ __launch_bounds__(512, 4) void vq_main(const float* __restrict__ x,
                                                  const float* __restrict__ cb,
                                                  const float* __restrict__ Cn,
                                                  const float* __restrict__ cbT,
                                                  unsigned int* __restrict__ counts,
                                                  float* __restrict__ lossSum,
                                                  float* __restrict__ out)
{
    __shared__ float ecb[DIM * KT];   // 64 KB codebook k-tile, [d][k] row-major
    const int tid = threadIdx.x;
    const int tc  = tid & 63;         // lane
    const int tr  = tid >> 6;         // wave id — NOT readfirstlane'd: keep x loads VECTOR
    const int rowBase = blockIdx.x * ROWTILE + tr * TR;
    const float* xw = x + (size_t)rowBase * DIM;

    // A[i] = ||x_row||^2 via butterfly (all lanes end with the value)
    float A[TR];
    #pragma unroll
    for (int i = 0; i < TR; ++i) {
        float v = xw[i * DIM + tc];
        float p = v * v;
        #pragma unroll
        for (int s = 1; s < 64; s <<= 1) p += __shfl_xor(p, s, 64);
        A[i] = p;
    }

    float bestD[TR]; int bestK[TR];
    #pragma unroll
    for (int i = 0; i < TR; ++i) { bestD[i] = 3.4e38f; bestK[i] = 0; }

    for (int kt = 0; kt < NUM_K; kt += KT) {
        __syncthreads();   // previous tile fully consumed
        {   // stage cb[d][kt..kt+KT) -> ecb[d][0..KT): 512 thr * 8 float4 = 64 KB
            const int dd = tid >> 3;        // 0..63 = d row (8 threads per row)
            const int m  = tid & 7;
            const float* src = cb + (size_t)dd * NUM_K + kt;
            float* dst = ecb + dd * KT;
            #pragma unroll
            for (int s = 0; s < 8; ++s) {
                int o = 4 * (m + 8 * s);
                *(float4*)(dst + o) = *(const float4*)(src + o);
            }
        }
        __syncthreads();

        // acc[i] = dot(x_row(i), e_col(kt + 4*tc + {0,1,2,3})), d ascending
        float4 acc[TR];
        #pragma unroll
        for (int i = 0; i < TR; ++i) acc[i] = float4{0.0f, 0.0f, 0.0f, 0.0f};

        #pragma unroll
        for (int ds = 0; ds < DIM; ds += 4) {
            float4 xv[TR];
            #pragma unroll
            for (int i = 0; i < TR; ++i)
                xv[i] = *(const float4*)(xw + i * DIM + ds);   // vector load, L1-hot
            #pragma unroll
            for (int d2 = 0; d2 < 4; ++d2) {
                float4 ev = *(const float4*)(ecb + (ds + d2) * KT + 4 * tc);
                #pragma unroll
                for (int i = 0; i < TR; ++i) {
                    float xs = (d2 == 0) ? xv[i].x : (d2 == 1) ? xv[i].y
                             : (d2 == 2) ? xv[i].z : xv[i].w;
                    acc[i].x = fmaf(xs, ev.x, acc[i].x);
                    acc[i].y = fmaf(xs, ev.y, acc[i].y);
                    acc[i].z = fmaf(xs, ev.z, acc[i].z);
                    acc[i].w = fmaf(xs, ev.w, acc[i].w);
                }
            }
        }

        // distances in the reference's op order: (||x||^2 - 2s) + ||e||^2
        // k scanned ascending (j components in order); strict < keeps first min
        const float4 Cv = *(const float4*)(Cn + kt + 4 * tc);
        #pragma unroll
        for (int i = 0; i < TR; ++i) {
            const int kb = kt + 4 * tc;
            float d0 = fmaf(-2.0f, acc[i].x, A[i]) + Cv.x;
            if (d0 < bestD[i]) { bestD[i] = d0; bestK[i] = kb + 0; }
            float d1 = fmaf(-2.0f, acc[i].y, A[i]) + Cv.y;
            if (d1 < bestD[i]) { bestD[i] = d1; bestK[i] = kb + 1; }
            float d2 = fmaf(-2.0f, acc[i].z, A[i]) + Cv.z;
            if (d2 < bestD[i]) { bestD[i] = d2; bestK[i] = kb + 2; }
            float d3 = fmaf(-2.0f, acc[i].w, A[i]) + Cv.w;
            if (d3 < bestD[i]) { bestD[i] = d3; bestK[i] = kb + 3; }
        }
    }

    // wave-wide lexicographic argmin per row (ties -> lowest k, like jnp.argmin)
    #pragma unroll
    for (int i = 0; i < TR; ++i) {
        float bd = bestD[i]; int bk = bestK[i];
        #pragma unroll
        for (int s = 1; s < 64; s <<= 1) {
            float od = __shfl_xor(bd, s, 64);
            int   ok = __shfl_xor(bk, s, 64);
            if (od < bd || (od == bd && ok < bk)) { bd = od; bk = ok; }
        }
        bestD[i] = bd; bestK[i] = bk;
    }

    // ste rows: x + (q - x); 64 lanes per row, coalesced 256 B
    #pragma unroll
    for (int i = 0; i < TR; ++i) {
        float q  = cbT[bestK[i] * DIM + tc];
        float xv = xw[i * DIM + tc];
        out[(size_t)(rowBase + i) * DIM + tc] = xv + (q - xv);
    }
    // histogram + loss (min distance IS the row's squared error); 1 atomic/wave
    if (tc == 0) {
        float s8 = 0.0f;
        #pragma unroll
        for (int i = 0; i < TR; ++i) {
            atomicAdd(&counts[bestK[i]], 1u);
            s8 += bestD[i];
        }
        atomicAdd(lossSum, s8);
    }
}

__global__ __launch_bounds__(512) void vq_final(const unsigned int* __restrict__ counts,
                                                const float* __restrict__ lossSum,
                                                float* __restrict__ out)
{
    __shared__ float wsum[8];
    int t = threadIdx.x;  // 0..511
    float p = (float)counts[t] * (1.0f / 65536.0f);
    float term = p * logf(p + 1e-10f);
    #pragma unroll
    for (int s = 1; s < 64; s <<= 1) term += __shfl_xor(term, s, 64);
    if ((t & 63) == 0) wsum[t >> 6] = term;
    __syncthreads();
    if (t == 0) {
        float s = 0.0f;
        #pragma unroll
        for (int w = 0; w < 8; ++w) s += wsum[w];
        out[NELEM] = expf(-s);                       // perplexity
        float m = (*lossSum) * (1.0f / (float)NELEM);
        out[NELEM + 1] = m;                          // codebook loss
        out[NELEM + 2] = 0.25f * m;                  // commitment loss = BETA * m
    }
}

extern "C" void kernel_launch(void* const* d_in, const int* in_sizes, int n_in,
                              void* d_out, int out_size, void* d_ws, size_t ws_size,
                              hipStream_t stream)
{
    const float* x  = (const float*)d_in[0];   // [65536,64]
    const float* cb = (const float*)d_in[1];   // [64,512]
    float* out = (float*)d_out;

    float* wsf = (float*)d_ws;
    float* Cn  = wsf;                                   // 512
    float* cbT = wsf + NUM_K;                           // 512*64
    unsigned int* counts = (unsigned int*)(wsf + NUM_K + NUM_K * DIM);  // 512
    float* lossSum = (float*)(wsf + NUM_K + NUM_K * DIM + NUM_K);       // 1

    vq_prep <<<1,       512, 0, stream>>>(cb, Cn, cbT, counts, lossSum);
    vq_main <<<NBLOCKS, 512, 0, stream>>>(x, cb, Cn, cbT, counts, lossSum, out);
    vq_final<<<1,       512, 0, stream>>>(counts, lossSum, out);
}

// Round 4
// 158.610 us; speedup vs baseline: 5.2216x; 5.2216x over previous
//
#include <hip/hip_runtime.h>
#include <math.h>

// VectorQuantizer via bf16-split MFMA + exact-fp32 fallback.
// inputs: x [65536,64] f32, cb [64,512] f32.
// out (flat f32): ste[4194304] | perplexity | codebook_loss | commitment_loss
// ws: counts u32[512] @0 | lossSum f32 @2048   (uses only 2052 B)
// d_out doubles as scratch: per-row interleaved bf16 split (xh[64],xl[64] u16)
// occupying exactly each block's own 64KB output region (no cross-block hazard).

#define NUM_K  512
#define DIM    64
#define NROWS  65536
#define NELEM  (NROWS * DIM)
#define EPS    1e-3f

typedef __attribute__((ext_vector_type(8)))  short  short8;   // 8 bf16 (4 VGPR)
typedef __attribute__((ext_vector_type(16))) float  f32x16;   // MFMA acc
typedef __attribute__((ext_vector_type(4)))  unsigned int   uint4v;
typedef __attribute__((ext_vector_type(4)))  unsigned short us4v;

// LDS layout (dynamic, 133,632 B): Ebuf 16*8192 | Cn f32[512] | kstar u16[256]
#define LDS_EB 0
#define LDS_CN 131072
#define LDS_KS (131072 + 2048)
#define LDS_SZ (131072 + 2048 + 512)

static __device__ __forceinline__ unsigned short f2bf(float f) {
    unsigned u = __float_as_uint(f);
    u += 0x7fffu + ((u >> 16) & 1u);          // RNE
    return (unsigned short)(u >> 16);
}
static __device__ __forceinline__ float bf2f(unsigned short h) {
    return __uint_as_float(((unsigned)h) << 16);
}

// ---------------- prep: x -> interleaved bf16 split in d_out; zero counts/loss
__global__ __launch_bounds__(256) void vq_prep(const float* __restrict__ x,
                                               unsigned short* __restrict__ Xs,
                                               unsigned int* __restrict__ counts,
                                               float* __restrict__ lossSum)
{
    int idx = blockIdx.x * 256 + threadIdx.x;       // 0 .. 1048575
    int r = idx >> 4, g = idx & 15;
    float4 v = *(const float4*)(x + (size_t)r * DIM + g * 4);
    us4v h, l;
    {
        unsigned short h0 = f2bf(v.x); l.x = f2bf(v.x - bf2f(h0)); h.x = h0;
        unsigned short h1 = f2bf(v.y); l.y = f2bf(v.y - bf2f(h1)); h.y = h1;
        unsigned short h2 = f2bf(v.z); l.z = f2bf(v.z - bf2f(h2)); h.z = h2;
        unsigned short h3 = f2bf(v.w); l.w = f2bf(v.w - bf2f(h3)); h.w = h3;
    }
    *(us4v*)(Xs + (size_t)r * 128 + g * 4)      = h;
    *(us4v*)(Xs + (size_t)r * 128 + 64 + g * 4) = l;
    if (blockIdx.x == 0) {
        int t = threadIdx.x;
        counts[t] = 0u; counts[256 + t] = 0u;
        if (t == 0) *lossSum = 0.0f;
    }
}

// ---------------- exact fallback: half-wave (32 lanes) full rescan of one row.
// Bit-identical to the round-2 verified computation (matched numpy, absmax 0).
static __device__ __forceinline__ int halfScan(const float* __restrict__ x,
                                               const float* __restrict__ cb,
                                               const float* __restrict__ CnL,
                                               int row, int j)
{
    // A = ||x_row||^2, same tree order as 64-lane butterfly (strides 1..32)
    float v0 = x[(size_t)row * DIM + j];
    float v1 = x[(size_t)row * DIM + 32 + j];
    float p0 = v0 * v0, p1 = v1 * v1;
    #pragma unroll
    for (int s = 1; s < 32; s <<= 1) { p0 += __shfl_xor(p0, s, 64); p1 += __shfl_xor(p1, s, 64); }
    float A = p0 + p1;

    float sacc[16];
    #pragma unroll
    for (int c = 0; c < 16; ++c) sacc[c] = 0.0f;
    #pragma unroll 4
    for (int d = 0; d < DIM; ++d) {                  // ascending-d fp32 chains
        float xv = x[(size_t)row * DIM + d];
        const float* eb = cb + (size_t)d * NUM_K + j * 16;
        float4 e0 = *(const float4*)(eb);
        float4 e1 = *(const float4*)(eb + 4);
        float4 e2 = *(const float4*)(eb + 8);
        float4 e3 = *(const float4*)(eb + 12);
        sacc[0]  = fmaf(xv, e0.x, sacc[0]);  sacc[1]  = fmaf(xv, e0.y, sacc[1]);
        sacc[2]  = fmaf(xv, e0.z, sacc[2]);  sacc[3]  = fmaf(xv, e0.w, sacc[3]);
        sacc[4]  = fmaf(xv, e1.x, sacc[4]);  sacc[5]  = fmaf(xv, e1.y, sacc[5]);
        sacc[6]  = fmaf(xv, e1.z, sacc[6]);  sacc[7]  = fmaf(xv, e1.w, sacc[7]);
        sacc[8]  = fmaf(xv, e2.x, sacc[8]);  sacc[9]  = fmaf(xv, e2.y, sacc[9]);
        sacc[10] = fmaf(xv, e2.z, sacc[10]); sacc[11] = fmaf(xv, e2.w, sacc[11]);
        sacc[12] = fmaf(xv, e3.x, sacc[12]); sacc[13] = fmaf(xv, e3.y, sacc[13]);
        sacc[14] = fmaf(xv, e3.z, sacc[14]); sacc[15] = fmaf(xv, e3.w, sacc[15]);
    }
    unsigned long long best = ~0ull;
    #pragma unroll
    for (int c = 0; c < 16; ++c) {
        int k = j * 16 + c;
        float dd = fmaf(-2.0f, sacc[c], A) + CnL[k];
        unsigned long long pk = (((unsigned long long)__float_as_uint(dd)) << 32) | (unsigned)k;
        best = pk < best ? pk : best;
    }
    #pragma unroll
    for (int s = 1; s < 32; s <<= 1) {
        unsigned long long o = __shfl_xor(best, s, 64);
        best = o < best ? o : best;
    }
    return (int)(best & 0xffffffffu);
}

// ---------------- main: per block = 256 rows, full 512-code sweep via MFMA
__global__ __launch_bounds__(512, 2) void vq_main(const float* __restrict__ x,
                                                  const float* __restrict__ cb,
                                                  const unsigned short* __restrict__ Xs,
                                                  float* __restrict__ out,
                                                  unsigned int* __restrict__ counts,
                                                  float* __restrict__ lossSum)
{
    extern __shared__ char smem[];
    float* CnL = (float*)(smem + LDS_CN);
    unsigned short* ksL = (unsigned short*)(smem + LDS_KS);

    const int tid  = threadIdx.x;
    const int lane = tid & 63;
    const int w    = tid >> 6;          // wave 0..7
    const int half = lane >> 5;         // k-group half
    const int l31  = lane & 31;
    const int bRow0 = blockIdx.x * 256;

    // ---- P0: build split codebook in LDS (sections [hl*8 + (d>>3)][code][8 bf16])
    {
        const int k = tid;              // code 0..511
        float a = 0.0f;
        #pragma unroll
        for (int g = 0; g < 8; ++g) {
            uint4v hh, ll;
            unsigned hw[4], lw[4];
            #pragma unroll
            for (int m = 0; m < 4; ++m) {
                int d0 = g * 8 + 2 * m;
                float va = cb[(size_t)d0 * NUM_K + k];
                float vb = cb[(size_t)(d0 + 1) * NUM_K + k];
                a = fmaf(va, va, a);                 // ascending-d chain (= round-2 prep)
                a = fmaf(vb, vb, a);
                unsigned short ha = f2bf(va), hb = f2bf(vb);
                unsigned short la = f2bf(va - bf2f(ha)), lb = f2bf(vb - bf2f(hb));
                hw[m] = (unsigned)ha | ((unsigned)hb << 16);
                lw[m] = (unsigned)la | ((unsigned)lb << 16);
            }
            hh.x = hw[0]; hh.y = hw[1]; hh.z = hw[2]; hh.w = hw[3];
            ll.x = lw[0]; ll.y = lw[1]; ll.z = lw[2]; ll.w = lw[3];
            *(uint4v*)(smem + (size_t)g * 8192 + k * 16)        = hh;
            *(uint4v*)(smem + (size_t)(8 + g) * 8192 + k * 16)  = ll;
        }
        CnL[k] = a;
    }
    __syncthreads();

    // ---- P1: sweep. A-frags for this lane's row (held in regs all sweep).
    {
        const int rowT = bRow0 + w * 32 + l31;
        const unsigned short* Xr = Xs + (size_t)rowT * 128;
        short8 ah[4], al[4];
        #pragma unroll
        for (int ks = 0; ks < 4; ++ks) {
            ah[ks] = *(const short8*)(Xr + ks * 16 + half * 8);
            al[ks] = *(const short8*)(Xr + 64 + ks * 16 + half * 8);
        }
        float d1[16], d2[16]; int k1[16];
        #pragma unroll
        for (int r = 0; r < 16; ++r) { d1[r] = 3.4e38f; d2[r] = 3.4e38f; k1[r] = 0; }

        #pragma unroll 1
        for (int ct = 0; ct < 16; ++ct) {
            f32x16 acc = (f32x16)0.0f;
            const char* bbase = smem + ct * 512 + l31 * 16;
            #pragma unroll
            for (int ks = 0; ks < 4; ++ks) {
                short8 bh = *(const short8*)(bbase + (size_t)(ks * 2 + half) * 8192);
                short8 bl = *(const short8*)(bbase + (size_t)(8 + ks * 2 + half) * 8192);
                acc = __builtin_amdgcn_mfma_f32_32x32x16_bf16(ah[ks], bh, acc, 0, 0, 0);
                acc = __builtin_amdgcn_mfma_f32_32x32x16_bf16(ah[ks], bl, acc, 0, 0, 0);
                acc = __builtin_amdgcn_mfma_f32_32x32x16_bf16(al[ks], bh, acc, 0, 0, 0);
                acc = __builtin_amdgcn_mfma_f32_32x32x16_bf16(al[ks], bl, acc, 0, 0, 0);
            }
            float cv = CnL[ct * 32 + l31];
            int kcol = ct * 32 + l31;
            #pragma unroll
            for (int r = 0; r < 16; ++r) {
                float d = fmaf(-2.0f, acc[r], cv);   // rank on C - 2S (A drops out)
                bool c = d < d1[r];
                d2[r] = c ? d1[r] : fminf(d, d2[r]);
                k1[r] = c ? kcol : k1[r];
                d1[r] = c ? d : d1[r];
            }
        }
        // merge (d1,k1,d2) across the 32 lanes of each half (strides 1..16)
        #pragma unroll
        for (int r = 0; r < 16; ++r) {
            #pragma unroll
            for (int s = 1; s < 32; s <<= 1) {
                float o1 = __shfl_xor(d1[r], s, 64);
                int   ok = __shfl_xor(k1[r], s, 64);
                float o2 = __shfl_xor(d2[r], s, 64);
                float n1 = fminf(d1[r], o1);
                float n2 = fminf(fmaxf(d1[r], o1), fminf(d2[r], o2));
                int   nk = (o1 < d1[r]) ? ok : ((d1[r] < o1) ? k1[r] : min(k1[r], ok));
                d1[r] = n1; d2[r] = n2; k1[r] = nk;
            }
        }
        // certify or exact-fallback; write kstar
        #pragma unroll 1
        for (int r = 0; r < 16; ++r) {
            int rowLocal = (r & 3) + 8 * (r >> 2) + 4 * half;   // m74/m101 C-layout
            int grow = bRow0 + w * 32 + rowLocal;
            if (d2[r] - d1[r] <= EPS) {                         // half-uniform branch
                k1[r] = halfScan(x, cb, CnL, grow, l31);
            }
            if (l31 == 0) ksL[w * 32 + rowLocal] = (unsigned short)k1[r];
        }
    }
    __syncthreads();

    // ---- P2: ste + loss + histogram (overwrites this block's own Xs region)
    {
        float lacc = 0.0f;
        #pragma unroll 4
        for (int rr = 0; rr < 32; ++rr) {
            int row = bRow0 + w * 32 + rr;
            int kst = ksL[w * 32 + rr];
            float q  = cb[(size_t)lane * NUM_K + kst];
            float xv = x[(size_t)row * DIM + lane];
            float dlt = q - xv;
            out[(size_t)row * DIM + lane] = xv + dlt;           // x + (q - x)
            lacc = fmaf(dlt, dlt, lacc);
            if (lane == 0) atomicAdd(&counts[kst], 1u);
        }
        #pragma unroll
        for (int s = 1; s < 64; s <<= 1) lacc += __shfl_xor(lacc, s, 64);
        if (lane == 0) atomicAdd(lossSum, lacc);
    }
}

// ---------------- final: perplexity + losses
__global__ __launch_bounds__(512) void vq_final(const unsigned int* __restrict__ counts,
                                                const float* __restrict__ lossSum,
                                                float* __restrict__ out)
{
    __shared__ float wsum[8];
    int t = threadIdx.x;
    float p = (float)counts[t] * (1.0f / 65536.0f);
    float term = p * logf(p + 1e-10f);
    #pragma unroll
    for (int s = 1; s < 64; s <<= 1) term += __shfl_xor(term, s, 64);
    if ((t & 63) == 0) wsum[t >> 6] = term;
    __syncthreads();
    if (t == 0) {
        float s = 0.0f;
        #pragma unroll
        for (int w = 0; w < 8; ++w) s += wsum[w];
        out[NELEM] = expf(-s);
        float m = (*lossSum) * (1.0f / (float)NELEM);
        out[NELEM + 1] = m;
        out[NELEM + 2] = 0.25f * m;
    }
}

extern "C" void kernel_launch(void* const* d_in, const int* in_sizes, int n_in,
                              void* d_out, int out_size, void* d_ws, size_t ws_size,
                              hipStream_t stream)
{
    const float* x  = (const float*)d_in[0];
    const float* cb = (const float*)d_in[1];
    float* out = (float*)d_out;
    unsigned short* Xs = (unsigned short*)d_out;     // split scratch aliases output
    unsigned int* counts = (unsigned int*)d_ws;
    float* lossSum = (float*)((char*)d_ws + 2048);

    vq_prep <<<4096, 256, 0,      stream>>>(x, Xs, counts, lossSum);
    vq_main <<<256,  512, LDS_SZ, stream>>>(x, cb, Xs, out, counts, lossSum);
    vq_final<<<1,    512, 0,      stream>>>(counts, lossSum, out);
}

// Round 6
// 151.218 us; speedup vs baseline: 5.4768x; 1.0489x over previous
//
#include <hip/hip_runtime.h>
#include <math.h>

// VectorQuantizer via bf16-split MFMA + exact-fp32 fallback (fused single main).
// inputs: x [65536,64] f32, cb [64,512] f32.
// out (flat f32): ste[4194304] | perplexity | codebook_loss | commitment_loss
// ws: counts u32[512] @0 | lossSum f32 @2048  (zeroed via hipMemsetAsync)

#define NUM_K  512
#define DIM    64
#define NROWS  65536
#define NELEM  (NROWS * DIM)
#define EPS    1e-3f

typedef __attribute__((ext_vector_type(8)))  short  short8;   // 8 bf16 (4 VGPR)
typedef __attribute__((ext_vector_type(16))) float  f32x16;   // MFMA acc
typedef __attribute__((ext_vector_type(4)))  unsigned int   uint4v;

// LDS: region0 [0,133120): xstage(64KB) -> Ebuf(128KB) -> cbT f32[512][65]
//      CnL f32[512] @133120 | ksL u16[256] @135168 ; total 135,680 B
#define LDS_CN 133120
#define LDS_KS 135168
#define LDS_SZ 135680

static __device__ __forceinline__ unsigned short f2bf(float f) {
    unsigned u = __float_as_uint(f);
    u += 0x7fffu + ((u >> 16) & 1u);          // RNE
    return (unsigned short)(u >> 16);
}
static __device__ __forceinline__ float bf2f(unsigned short h) {
    return __uint_as_float(((unsigned)h) << 16);
}

// exact fallback: half-wave (32 lanes) full rescan of one row.
// Bit-identical to the round-2/4 verified computation.
static __device__ __forceinline__ int halfScan(const float* __restrict__ x,
                                               const float* __restrict__ cb,
                                               const float* __restrict__ CnL,
                                               int row, int j)
{
    float v0 = x[(size_t)row * DIM + j];
    float v1 = x[(size_t)row * DIM + 32 + j];
    float p0 = v0 * v0, p1 = v1 * v1;
    #pragma unroll
    for (int s = 1; s < 32; s <<= 1) { p0 += __shfl_xor(p0, s, 64); p1 += __shfl_xor(p1, s, 64); }
    float A = p0 + p1;

    float sacc[16];
    #pragma unroll
    for (int c = 0; c < 16; ++c) sacc[c] = 0.0f;
    #pragma unroll 4
    for (int d = 0; d < DIM; ++d) {
        float xv = x[(size_t)row * DIM + d];
        const float* eb = cb + (size_t)d * NUM_K + j * 16;
        float4 e0 = *(const float4*)(eb);
        float4 e1 = *(const float4*)(eb + 4);
        float4 e2 = *(const float4*)(eb + 8);
        float4 e3 = *(const float4*)(eb + 12);
        sacc[0]  = fmaf(xv, e0.x, sacc[0]);  sacc[1]  = fmaf(xv, e0.y, sacc[1]);
        sacc[2]  = fmaf(xv, e0.z, sacc[2]);  sacc[3]  = fmaf(xv, e0.w, sacc[3]);
        sacc[4]  = fmaf(xv, e1.x, sacc[4]);  sacc[5]  = fmaf(xv, e1.y, sacc[5]);
        sacc[6]  = fmaf(xv, e1.z, sacc[6]);  sacc[7]  = fmaf(xv, e1.w, sacc[7]);
        sacc[8]  = fmaf(xv, e2.x, sacc[8]);  sacc[9]  = fmaf(xv, e2.y, sacc[9]);
        sacc[10] = fmaf(xv, e2.z, sacc[10]); sacc[11] = fmaf(xv, e2.w, sacc[11]);
        sacc[12] = fmaf(xv, e3.x, sacc[12]); sacc[13] = fmaf(xv, e3.y, sacc[13]);
        sacc[14] = fmaf(xv, e3.z, sacc[14]); sacc[15] = fmaf(xv, e3.w, sacc[15]);
    }
    unsigned long long best = ~0ull;
    #pragma unroll
    for (int c = 0; c < 16; ++c) {
        int k = j * 16 + c;
        float dd = fmaf(-2.0f, sacc[c], A) + CnL[k];
        unsigned long long pk = (((unsigned long long)__float_as_uint(dd)) << 32) | (unsigned)k;
        best = pk < best ? pk : best;
    }
    #pragma unroll
    for (int s = 1; s < 32; s <<= 1) {
        unsigned long long o = __shfl_xor(best, s, 64);
        best = o < best ? o : best;
    }
    return (int)(best & 0xffffffffu);
}

__global__ __launch_bounds__(512, 2) void vq_main(const float* __restrict__ x,
                                                  const float* __restrict__ cb,
                                                  float* __restrict__ out,
                                                  unsigned int* __restrict__ counts,
                                                  float* __restrict__ lossSum)
{
    extern __shared__ char smem[];
    float* CnL = (float*)(smem + LDS_CN);
    unsigned short* ksL = (unsigned short*)(smem + LDS_KS);
    float* xst = (float*)smem;     // phase A
    float* cbT = (float*)smem;     // phase P2

    const int tid  = threadIdx.x;
    const int lane = tid & 63;
    const int w    = tid >> 6;          // wave 0..7
    const int half = lane >> 5;
    const int l31  = lane & 31;
    const int bRow0 = blockIdx.x * 256;

    // ---- A: stage this block's 256 x-rows into LDS (swizzled 16B granules)
    // 256 rows * 16 float4-granules = 4096 granules = 8 iters * 512 threads.
    {
        const float* xsrc = x + (size_t)bRow0 * DIM;
        #pragma unroll
        for (int i = 0; i < 8; ++i) {
            int f = i * 512 + tid;              // float4 index 0..4095
            int row = f >> 4, g = f & 15;
            float4 v = *(const float4*)(xsrc + (size_t)f * 4);
            *(float4*)(xst + (size_t)(row * 16 + (g ^ (row & 15))) * 4) = v;
        }
    }
    __syncthreads();

    // ---- A2: per-lane row -> bf16 split frags in regs (identical RNE split)
    short8 ah[4], al[4];
    {
        const int r = w * 32 + l31;
        #pragma unroll
        for (int ks = 0; ks < 4; ++ks) {
            int g0 = ks * 4 + half * 2;
            float4 f0 = *(const float4*)(xst + (size_t)(r * 16 + ((g0    ) ^ (r & 15))) * 4);
            float4 f1 = *(const float4*)(xst + (size_t)(r * 16 + ((g0 + 1) ^ (r & 15))) * 4);
            float fv[8] = { f0.x, f0.y, f0.z, f0.w, f1.x, f1.y, f1.z, f1.w };
            #pragma unroll
            for (int j = 0; j < 8; ++j) {
                unsigned short hh = f2bf(fv[j]);
                unsigned short ll = f2bf(fv[j] - bf2f(hh));
                ah[ks][j] = (short)hh;
                al[ks][j] = (short)ll;
            }
        }
    }
    __syncthreads();   // xstage reads done before Ebuf overwrites

    // ---- B: build split codebook in LDS (proven round-4 P0, bit-identical)
    {
        const int k = tid;              // code 0..511
        float a = 0.0f;
        #pragma unroll
        for (int g = 0; g < 8; ++g) {
            uint4v hh, ll;
            unsigned hw[4], lw[4];
            #pragma unroll
            for (int m = 0; m < 4; ++m) {
                int d0 = g * 8 + 2 * m;
                float va = cb[(size_t)d0 * NUM_K + k];
                float vb = cb[(size_t)(d0 + 1) * NUM_K + k];
                a = fmaf(va, va, a);
                a = fmaf(vb, vb, a);
                unsigned short ha = f2bf(va), hb = f2bf(vb);
                unsigned short la = f2bf(va - bf2f(ha)), lb = f2bf(vb - bf2f(hb));
                hw[m] = (unsigned)ha | ((unsigned)hb << 16);
                lw[m] = (unsigned)la | ((unsigned)lb << 16);
            }
            hh.x = hw[0]; hh.y = hw[1]; hh.z = hw[2]; hh.w = hw[3];
            ll.x = lw[0]; ll.y = lw[1]; ll.z = lw[2]; ll.w = lw[3];
            *(uint4v*)(smem + (size_t)g * 8192 + k * 16)        = hh;
            *(uint4v*)(smem + (size_t)(8 + g) * 8192 + k * 16)  = ll;
        }
        CnL[k] = a;
    }
    __syncthreads();

    // ---- P1: sweep (proven round-4 code; frags already in regs)
    {
        float d1[16], d2[16]; int k1[16];
        #pragma unroll
        for (int r = 0; r < 16; ++r) { d1[r] = 3.4e38f; d2[r] = 3.4e38f; k1[r] = 0; }

        #pragma unroll 1
        for (int ct = 0; ct < 16; ++ct) {
            f32x16 acc = (f32x16)0.0f;
            const char* bbase = smem + ct * 512 + l31 * 16;
            #pragma unroll
            for (int ks = 0; ks < 4; ++ks) {
                short8 bh = *(const short8*)(bbase + (size_t)(ks * 2 + half) * 8192);
                short8 bl = *(const short8*)(bbase + (size_t)(8 + ks * 2 + half) * 8192);
                acc = __builtin_amdgcn_mfma_f32_32x32x16_bf16(ah[ks], bh, acc, 0, 0, 0);
                acc = __builtin_amdgcn_mfma_f32_32x32x16_bf16(ah[ks], bl, acc, 0, 0, 0);
                acc = __builtin_amdgcn_mfma_f32_32x32x16_bf16(al[ks], bh, acc, 0, 0, 0);
                acc = __builtin_amdgcn_mfma_f32_32x32x16_bf16(al[ks], bl, acc, 0, 0, 0);
            }
            float cv = CnL[ct * 32 + l31];
            int kcol = ct * 32 + l31;
            #pragma unroll
            for (int r = 0; r < 16; ++r) {
                float d = fmaf(-2.0f, acc[r], cv);   // rank on C - 2S
                bool c = d < d1[r];
                d2[r] = c ? d1[r] : fminf(d, d2[r]);
                k1[r] = c ? kcol : k1[r];
                d1[r] = c ? d : d1[r];
            }
        }
        #pragma unroll
        for (int r = 0; r < 16; ++r) {
            #pragma unroll
            for (int s = 1; s < 32; s <<= 1) {
                float o1 = __shfl_xor(d1[r], s, 64);
                int   ok = __shfl_xor(k1[r], s, 64);
                float o2 = __shfl_xor(d2[r], s, 64);
                float n1 = fminf(d1[r], o1);
                float n2 = fminf(fmaxf(d1[r], o1), fminf(d2[r], o2));
                int   nk = (o1 < d1[r]) ? ok : ((d1[r] < o1) ? k1[r] : min(k1[r], ok));
                d1[r] = n1; d2[r] = n2; k1[r] = nk;
            }
        }
        #pragma unroll 1
        for (int r = 0; r < 16; ++r) {
            int rowLocal = (r & 3) + 8 * (r >> 2) + 4 * half;   // verified C-layout
            int grow = bRow0 + w * 32 + rowLocal;
            if (d2[r] - d1[r] <= EPS) {
                k1[r] = halfScan(x, cb, CnL, grow, l31);
            }
            if (l31 == 0) ksL[w * 32 + rowLocal] = (unsigned short)k1[r];
        }
    }
    __syncthreads();   // P1 Ebuf reads + ksL writes complete

    // ---- P2a: rebuild region as transposed f32 codebook [512][65]
    {
        const int k = tid;
        #pragma unroll 8
        for (int d = 0; d < DIM; ++d)
            cbT[(size_t)k * 65 + d] = cb[(size_t)d * NUM_K + k];
    }
    __syncthreads();

    // ---- P2b: ste + loss + histogram, fully coalesced
    {
        float lacc = 0.0f;
        #pragma unroll 4
        for (int rr = 0; rr < 32; ++rr) {
            int row = bRow0 + w * 32 + rr;
            int kst = ksL[w * 32 + rr];
            float q  = cbT[(size_t)kst * 65 + lane];
            float xv = x[(size_t)row * DIM + lane];
            float dlt = q - xv;
            out[(size_t)row * DIM + lane] = xv + dlt;           // x + (q - x)
            lacc = fmaf(dlt, dlt, lacc);
            if (lane == 0) atomicAdd(&counts[kst], 1u);
        }
        #pragma unroll
        for (int s = 1; s < 64; s <<= 1) lacc += __shfl_xor(lacc, s, 64);
        if (lane == 0) atomicAdd(lossSum, lacc);
    }
}

__global__ __launch_bounds__(512) void vq_final(const unsigned int* __restrict__ counts,
                                                const float* __restrict__ lossSum,
                                                float* __restrict__ out)
{
    __shared__ float wsum[8];
    int t = threadIdx.x;
    float p = (float)counts[t] * (1.0f / 65536.0f);
    float term = p * logf(p + 1e-10f);
    #pragma unroll
    for (int s = 1; s < 64; s <<= 1) term += __shfl_xor(term, s, 64);
    if ((t & 63) == 0) wsum[t >> 6] = term;
    __syncthreads();
    if (t == 0) {
        float s = 0.0f;
        #pragma unroll
        for (int w = 0; w < 8; ++w) s += wsum[w];
        out[NELEM] = expf(-s);
        float m = (*lossSum) * (1.0f / (float)NELEM);
        out[NELEM + 1] = m;
        out[NELEM + 2] = 0.25f * m;
    }
}

extern "C" void kernel_launch(void* const* d_in, const int* in_sizes, int n_in,
                              void* d_out, int out_size, void* d_ws, size_t ws_size,
                              hipStream_t stream)
{
    const float* x  = (const float*)d_in[0];
    const float* cb = (const float*)d_in[1];
    float* out = (float*)d_out;
    unsigned int* counts = (unsigned int*)d_ws;
    float* lossSum = (float*)((char*)d_ws + 2048);

    hipMemsetAsync(d_ws, 0, 2052, stream);          // counts + lossSum
    vq_main <<<256, 512, LDS_SZ, stream>>>(x, cb, out, counts, lossSum);
    vq_final<<<1,   512, 0,      stream>>>(counts, lossSum, out);
}